// Round 1
// baseline (869.758 us; speedup 1.0000x reference)
//
#include <hip/hip_runtime.h>
#include <stdint.h>

#define H 4096

typedef float v4f __attribute__((ext_vector_type(4)));
typedef long long i64;

__device__ __forceinline__ void gload16(const uint8_t* g, uint8_t* l) {
  __builtin_amdgcn_global_load_lds(
      (const __attribute__((address_space(1))) uint8_t*)g,
      (__attribute__((address_space(3))) uint8_t*)l, 16, 0, 0);
}

// ---- weights: fp32 [k][n] -> fp8 transposed [n][k] (values already fp8-representable) ----
__global__ __launch_bounds__(256) void conv_w_kernel(
    const float* __restrict__ w0, const float* __restrict__ w1,
    const float* __restrict__ w2, uint8_t* __restrict__ o0,
    uint8_t* __restrict__ o1, uint8_t* __restrict__ o2) {
  const float* w = (blockIdx.z == 0) ? w0 : (blockIdx.z == 1 ? w1 : w2);
  uint8_t* o = (blockIdx.z == 0) ? o0 : (blockIdx.z == 1 ? o1 : o2);
  __shared__ uint8_t t[64][68];
  const int tid = threadIdx.x;
  const int k0 = blockIdx.y * 64, n0 = blockIdx.x * 64;
  const int rr = tid >> 4, cc = (tid & 15) * 4;
#pragma unroll
  for (int j = 0; j < 4; ++j) {
    const int r = rr + j * 16;
    v4f f = *(const v4f*)(w + (size_t)(k0 + r) * H + n0 + cc);
    unsigned p = __builtin_amdgcn_cvt_pk_fp8_f32(f.x, f.y, 0, false);
    p = __builtin_amdgcn_cvt_pk_fp8_f32(f.z, f.w, p, true);
    t[cc + 0][r] = p & 0xff;
    t[cc + 1][r] = (p >> 8) & 0xff;
    t[cc + 2][r] = (p >> 16) & 0xff;
    t[cc + 3][r] = p >> 24;
  }
  __syncthreads();
#pragma unroll
  for (int j = 0; j < 4; ++j) {
    const int n = rr + j * 16;
    unsigned p = (unsigned)t[n][cc] | ((unsigned)t[n][cc + 1] << 8) |
                 ((unsigned)t[n][cc + 2] << 16) |
                 ((unsigned)t[n][cc + 3] << 24);
    *(unsigned*)(o + (size_t)(n0 + n) * H + k0 + cc) = p;
  }
}

// ---- row kernel: (optional relu) + rmsnorm + group-128 fp8 quant ----
__global__ __launch_bounds__(256) void quant_kernel(
    const float* in, const float* __restrict__ nw, uint8_t* __restrict__ q,
    float* __restrict__ sx, const int relu) {
  const int row = blockIdx.x, tid = threadIdx.x;
  const v4f* rp = (const v4f*)(in + (size_t)row * H);
  v4f v[4];
  float ss = 0.f;
#pragma unroll
  for (int j = 0; j < 4; ++j) {
    v4f x = rp[j * 256 + tid];
    if (relu) {
      x.x = fmaxf(x.x, 0.f); x.y = fmaxf(x.y, 0.f);
      x.z = fmaxf(x.z, 0.f); x.w = fmaxf(x.w, 0.f);
    }
    v[j] = x;
    ss += x.x * x.x + x.y * x.y + x.z * x.z + x.w * x.w;
  }
#pragma unroll
  for (int o = 32; o > 0; o >>= 1) ss += __shfl_down(ss, o);
  __shared__ float red[4];
  if ((tid & 63) == 0) red[tid >> 6] = ss;
  __syncthreads();
  ss = red[0] + red[1] + red[2] + red[3];
  const float rinv = 1.f / sqrtf(ss * (1.f / H) + 1e-6f);
#pragma unroll
  for (int j = 0; j < 4; ++j) {
    v4f nv = ((const v4f*)nw)[j * 256 + tid];
    v4f y;
    y.x = v[j].x * rinv * nv.x;
    y.y = v[j].y * rinv * nv.y;
    y.z = v[j].z * rinv * nv.z;
    y.w = v[j].w * rinv * nv.w;
    float am = fmaxf(fmaxf(fabsf(y.x), fabsf(y.y)), fmaxf(fabsf(y.z), fabsf(y.w)));
#pragma unroll
    for (int o = 16; o > 0; o >>= 1) am = fmaxf(am, __shfl_xor(am, o, 32));
    const float s = fmaxf(am, 1e-12f) / 448.f;  // true div: match ref bit-exact
    unsigned p = __builtin_amdgcn_cvt_pk_fp8_f32(y.x / s, y.y / s, 0, false);
    p = __builtin_amdgcn_cvt_pk_fp8_f32(y.z / s, y.w / s, p, true);
    ((unsigned*)q)[(size_t)row * 1024 + j * 256 + tid] = p;
    if ((tid & 31) == 0) sx[row * 32 + j * 8 + (tid >> 5)] = s;
  }
}

// ---- final rmsnorm, in-place on d_out ----
__global__ __launch_bounds__(256) void norm_kernel(float* io,
                                                   const float* __restrict__ nw) {
  const int row = blockIdx.x, tid = threadIdx.x;
  v4f* rp = (v4f*)(io + (size_t)row * H);
  v4f v[4];
  float ss = 0.f;
#pragma unroll
  for (int j = 0; j < 4; ++j) {
    v4f x = rp[j * 256 + tid];
    v[j] = x;
    ss += x.x * x.x + x.y * x.y + x.z * x.z + x.w * x.w;
  }
#pragma unroll
  for (int o = 32; o > 0; o >>= 1) ss += __shfl_down(ss, o);
  __shared__ float red[4];
  if ((tid & 63) == 0) red[tid >> 6] = ss;
  __syncthreads();
  ss = red[0] + red[1] + red[2] + red[3];
  const float rinv = 1.f / sqrtf(ss * (1.f / H) + 1e-6f);
#pragma unroll
  for (int j = 0; j < 4; ++j) {
    v4f nv = ((const v4f*)nw)[j * 256 + tid];
    v4f y;
    y.x = v[j].x * rinv * nv.x;
    y.y = v[j].y * rinv * nv.y;
    y.z = v[j].z * rinv * nv.z;
    y.w = v[j].w * rinv * nv.w;
    rp[j * 256 + tid] = y;
  }
}

// ---- block-scaled fp8 GEMM: C = sum_kb comb[kb][m] * (qa_kb @ wtT_kb), + resid ----
__global__ __launch_bounds__(256) void gemm_kernel(
    const uint8_t* __restrict__ qa,  // [M][K] fp8 activations
    const float* __restrict__ sx,    // [M][32] act scales
    const uint8_t* __restrict__ wt,  // [N][K] fp8 weight (transposed)
    const float* __restrict__ ws,    // [32][32] weight scales [kb][nb]
    const float* resid, float* outp, const int relu) {
  __shared__ __attribute__((aligned(16))) uint8_t sA[16384];
  __shared__ __attribute__((aligned(16))) uint8_t sB[16384];
  __shared__ __attribute__((aligned(16))) float comb[4096];  // [kb][m] 32x128

  const int tid = threadIdx.x;
  const int n0 = blockIdx.x * 128, m0 = blockIdx.y * 128;
  const int nb = blockIdx.x;

  // combined scale table for this tile: sx[m][kb] * ws[kb][nb]
  for (int idx = tid; idx < 4096; idx += 256) {
    const int kb = idx & 31, m = idx >> 5;
    comb[kb * 128 + m] = sx[(size_t)(m0 + m) * 32 + kb] * ws[kb * 32 + nb];
  }

  const int wv = tid >> 6, lane = tid & 63;
  const int quad = lane >> 4, l16 = lane & 15;
  const int wm = wv >> 1, wn = wv & 1;

  // staging: swizzle the GLOBAL chunk (LDS side of global_load_lds is fixed lane*16)
  const int swc = (tid & 7) ^ ((tid >> 3) & 7);
  const uint8_t* gA = qa + (size_t)(m0 + (tid >> 3)) * H + swc * 16;
  const uint8_t* gB = wt + (size_t)(n0 + (tid >> 3)) * H + swc * 16;
  uint8_t* lA = sA + wv * 1024;
  uint8_t* lB = sB + wv * 1024;

  // fragment LDS offsets (match the xor-16B-chunk swizzle); row&7 == l16&7
  int offk[4];
#pragma unroll
  for (int ks = 0; ks < 4; ++ks)
    offk[ks] = (((ks * 2 + (quad >> 1)) ^ (l16 & 7)) << 4) + (quad & 1) * 8;
  const int arow = (wm * 64 + l16) * 128;
  const int brow = (wn * 64 + l16) * 128;
  const float* combP = comb + wm * 64 + quad * 4;

  const v4f zf = {0.f, 0.f, 0.f, 0.f};
  v4f acc[4][4];
#pragma unroll
  for (int i = 0; i < 4; ++i)
#pragma unroll
    for (int j = 0; j < 4; ++j) acc[i][j] = zf;

  for (int kb = 0; kb < 32; ++kb) {
#pragma unroll
    for (int i = 0; i < 4; ++i) {
      gload16(gA + (size_t)i * (32 * H), lA + i * 4096);
      gload16(gB + (size_t)i * (32 * H), lB + i * 4096);
    }
    gA += 128;
    gB += 128;
    __syncthreads();

    i64 bf[4][4];
#pragma unroll
    for (int tc = 0; tc < 4; ++tc)
#pragma unroll
      for (int ks = 0; ks < 4; ++ks)
        bf[tc][ks] = *(const i64*)(sB + brow + tc * 2048 + offk[ks]);

#pragma unroll
    for (int tr = 0; tr < 4; ++tr) {
      i64 af[4];
#pragma unroll
      for (int ks = 0; ks < 4; ++ks)
        af[ks] = *(const i64*)(sA + arow + tr * 2048 + offk[ks]);
      const v4f s4 = *(const v4f*)(combP + kb * 128 + tr * 16);
#pragma unroll
      for (int tc = 0; tc < 4; ++tc) {
        v4f p = __builtin_amdgcn_mfma_f32_16x16x32_fp8_fp8(af[0], bf[tc][0], zf, 0, 0, 0);
        p = __builtin_amdgcn_mfma_f32_16x16x32_fp8_fp8(af[1], bf[tc][1], p, 0, 0, 0);
        p = __builtin_amdgcn_mfma_f32_16x16x32_fp8_fp8(af[2], bf[tc][2], p, 0, 0, 0);
        p = __builtin_amdgcn_mfma_f32_16x16x32_fp8_fp8(af[3], bf[tc][3], p, 0, 0, 0);
        acc[tr][tc] += p * s4;
      }
    }
    __syncthreads();
  }

  // epilogue: add residual (relu(x) for layer 0), write resid_out
  const int mB = m0 + wm * 64 + quad * 4;
  const int nB = n0 + wn * 64 + l16;
#pragma unroll
  for (int tr = 0; tr < 4; ++tr) {
#pragma unroll
    for (int r = 0; r < 4; ++r) {
      const size_t rowOff = (size_t)(mB + tr * 16 + r) * H;
#pragma unroll
      for (int tc = 0; tc < 4; ++tc) {
        const size_t idx = rowOff + nB + tc * 16;
        float rv = resid[idx];
        if (relu) rv = fmaxf(rv, 0.f);
        outp[idx] = acc[tr][tc][r] + rv;
      }
    }
  }
}

extern "C" void kernel_launch(void* const* d_in, const int* in_sizes, int n_in,
                              void* d_out, int out_size, void* d_ws, size_t ws_size,
                              hipStream_t stream) {
  const float* x   = (const float*)d_in[0];
  const float* w0  = (const float*)d_in[1];
  const float* ws0 = (const float*)d_in[2];
  const float* w1  = (const float*)d_in[3];
  const float* ws1 = (const float*)d_in[4];
  const float* w2  = (const float*)d_in[5];
  const float* ws2 = (const float*)d_in[6];
  const float* nw0 = (const float*)d_in[7];
  const float* nw1 = (const float*)d_in[8];
  const float* nw2 = (const float*)d_in[9];
  const float* nw3 = (const float*)d_in[10];
  float* R = (float*)d_out;  // residual lives in d_out (in-place)

  uint8_t* base = (uint8_t*)d_ws;
  uint8_t* wq0 = base;
  uint8_t* wq1 = base + ((size_t)16 << 20);
  uint8_t* wq2 = base + ((size_t)32 << 20);
  uint8_t* qa  = base + ((size_t)48 << 20);
  float* sa    = (float*)(base + ((size_t)64 << 20));

  conv_w_kernel<<<dim3(64, 64, 3), 256, 0, stream>>>(w0, w1, w2, wq0, wq1, wq2);

  quant_kernel<<<4096, 256, 0, stream>>>(x, nw0, qa, sa, 1);
  gemm_kernel<<<dim3(32, 32), 256, 0, stream>>>(qa, sa, wq0, ws0, x, R, 1);

  quant_kernel<<<4096, 256, 0, stream>>>(R, nw1, qa, sa, 0);
  gemm_kernel<<<dim3(32, 32), 256, 0, stream>>>(qa, sa, wq1, ws1, R, R, 0);

  quant_kernel<<<4096, 256, 0, stream>>>(R, nw2, qa, sa, 0);
  gemm_kernel<<<dim3(32, 32), 256, 0, stream>>>(qa, sa, wq2, ws2, R, R, 0);

  norm_kernel<<<4096, 256, 0, stream>>>(R, nw3);
}

// Round 2
// 685.387 us; speedup vs baseline: 1.2690x; 1.2690x over previous
//
#include <hip/hip_runtime.h>
#include <stdint.h>

#define H 4096

typedef float v4f __attribute__((ext_vector_type(4)));
typedef long long i64;
typedef long long v2l __attribute__((ext_vector_type(2)));

__device__ __forceinline__ void gload16(const uint8_t* g, uint8_t* l) {
  __builtin_amdgcn_global_load_lds(
      (const __attribute__((address_space(1))) uint8_t*)g,
      (__attribute__((address_space(3))) uint8_t*)l, 16, 0, 0);
}

// permuted byte position within a 128-B k-block: orig b = ks*32 + q*8 + j
// stored at q*32 + ks*8 + j  (so each lane's (q, ks) and (q, ks+1) fragments
// are 16 contiguous bytes -> ds_read_b128 in the GEMM)
__device__ __forceinline__ int permpos(int kg) {
  const int kb = kg >> 7, b = kg & 127;
  const int ks = b >> 5, q = (b >> 3) & 3, j = b & 7;
  return kb * 128 + q * 32 + ks * 8 + j;
}

// ---- weights: fp32 [k][n] -> fp8 transposed+permuted [n][perm(k)] ----
__global__ __launch_bounds__(256) void conv_w_kernel(
    const float* __restrict__ w0, const float* __restrict__ w1,
    const float* __restrict__ w2, uint8_t* __restrict__ o0,
    uint8_t* __restrict__ o1, uint8_t* __restrict__ o2) {
  const float* w = (blockIdx.z == 0) ? w0 : (blockIdx.z == 1 ? w1 : w2);
  uint8_t* o = (blockIdx.z == 0) ? o0 : (blockIdx.z == 1 ? o1 : o2);
  __shared__ uint8_t t[64][68];
  const int tid = threadIdx.x;
  const int k0 = blockIdx.y * 64, n0 = blockIdx.x * 64;
  const int rr = tid >> 4, cc = (tid & 15) * 4;
#pragma unroll
  for (int j = 0; j < 4; ++j) {
    const int r = rr + j * 16;
    v4f f = *(const v4f*)(w + (size_t)(k0 + r) * H + n0 + cc);
    unsigned p = __builtin_amdgcn_cvt_pk_fp8_f32(f.x, f.y, 0, false);
    p = __builtin_amdgcn_cvt_pk_fp8_f32(f.z, f.w, p, true);
    t[cc + 0][r] = p & 0xff;
    t[cc + 1][r] = (p >> 8) & 0xff;
    t[cc + 2][r] = (p >> 16) & 0xff;
    t[cc + 3][r] = p >> 24;
  }
  __syncthreads();
#pragma unroll
  for (int j = 0; j < 4; ++j) {
    const int n = rr + j * 16;
    unsigned p = (unsigned)t[n][cc] | ((unsigned)t[n][cc + 1] << 8) |
                 ((unsigned)t[n][cc + 2] << 16) |
                 ((unsigned)t[n][cc + 3] << 24);
    *(unsigned*)(o + (size_t)(n0 + n) * H + permpos(k0 + cc)) = p;
  }
}

// ---- row kernel: (optional relu) + rmsnorm + group-128 fp8 quant ----
// writes qa in permuted layout, scales transposed: sxT[kb][m]
__global__ __launch_bounds__(256) void quant_kernel(
    const float* in, const float* __restrict__ nw, uint8_t* __restrict__ q,
    float* __restrict__ sxT, const int relu) {
  const int row = blockIdx.x, tid = threadIdx.x;
  const v4f* rp = (const v4f*)(in + (size_t)row * H);
  v4f v[4];
  float ss = 0.f;
#pragma unroll
  for (int j = 0; j < 4; ++j) {
    v4f x = rp[j * 256 + tid];
    if (relu) {
      x.x = fmaxf(x.x, 0.f); x.y = fmaxf(x.y, 0.f);
      x.z = fmaxf(x.z, 0.f); x.w = fmaxf(x.w, 0.f);
    }
    v[j] = x;
    ss += x.x * x.x + x.y * x.y + x.z * x.z + x.w * x.w;
  }
#pragma unroll
  for (int o = 32; o > 0; o >>= 1) ss += __shfl_down(ss, o);
  __shared__ float red[4];
  if ((tid & 63) == 0) red[tid >> 6] = ss;
  __syncthreads();
  ss = red[0] + red[1] + red[2] + red[3];
  const float rinv = 1.f / sqrtf(ss * (1.f / H) + 1e-6f);
#pragma unroll
  for (int j = 0; j < 4; ++j) {
    v4f nv = ((const v4f*)nw)[j * 256 + tid];
    v4f y;
    y.x = v[j].x * rinv * nv.x;
    y.y = v[j].y * rinv * nv.y;
    y.z = v[j].z * rinv * nv.z;
    y.w = v[j].w * rinv * nv.w;
    float am = fmaxf(fmaxf(fabsf(y.x), fabsf(y.y)), fmaxf(fabsf(y.z), fabsf(y.w)));
#pragma unroll
    for (int o = 16; o > 0; o >>= 1) am = fmaxf(am, __shfl_xor(am, o, 32));
    const float s = fmaxf(am, 1e-12f) / 448.f;  // true div: match ref bit-exact
    unsigned p = __builtin_amdgcn_cvt_pk_fp8_f32(y.x / s, y.y / s, 0, false);
    p = __builtin_amdgcn_cvt_pk_fp8_f32(y.z / s, y.w / s, p, true);
    const int col = (j * 256 + tid) * 4;
    *(unsigned*)(q + (size_t)row * H + permpos(col)) = p;
    if ((tid & 31) == 0)
      sxT[(size_t)(j * 8 + (tid >> 5)) * 4096 + row] = s;
  }
}

// ---- final rmsnorm, in-place on d_out ----
__global__ __launch_bounds__(256) void norm_kernel(float* io,
                                                   const float* __restrict__ nw) {
  const int row = blockIdx.x, tid = threadIdx.x;
  v4f* rp = (v4f*)(io + (size_t)row * H);
  v4f v[4];
  float ss = 0.f;
#pragma unroll
  for (int j = 0; j < 4; ++j) {
    v4f x = rp[j * 256 + tid];
    v[j] = x;
    ss += x.x * x.x + x.y * x.y + x.z * x.z + x.w * x.w;
  }
#pragma unroll
  for (int o = 32; o > 0; o >>= 1) ss += __shfl_down(ss, o);
  __shared__ float red[4];
  if ((tid & 63) == 0) red[tid >> 6] = ss;
  __syncthreads();
  ss = red[0] + red[1] + red[2] + red[3];
  const float rinv = 1.f / sqrtf(ss * (1.f / H) + 1e-6f);
#pragma unroll
  for (int j = 0; j < 4; ++j) {
    v4f nv = ((const v4f*)nw)[j * 256 + tid];
    v4f y;
    y.x = v[j].x * rinv * nv.x;
    y.y = v[j].y * rinv * nv.y;
    y.z = v[j].z * rinv * nv.z;
    y.w = v[j].w * rinv * nv.w;
    rp[j * 256 + tid] = y;
  }
}

// ---- block-scaled fp8 GEMM on permuted tiles ----
__global__ __launch_bounds__(256, 4) void gemm_kernel(
    const uint8_t* __restrict__ qa,   // [M][perm(K)] fp8 activations
    const float* __restrict__ sxT,    // [32][M] act scales, transposed
    const uint8_t* __restrict__ wt,   // [N][perm(K)] fp8 weight
    const float* __restrict__ ws,     // [32][32] weight scales [kb][nb]
    const float* resid, float* outp, const int relu) {
  __shared__ __attribute__((aligned(16))) uint8_t sA[16384];
  __shared__ __attribute__((aligned(16))) uint8_t sB[16384];
  __shared__ __attribute__((aligned(16))) float scb[128];  // this kb's act scales
  __shared__ float ws_s[32];

  const int tid = threadIdx.x;
  const int n0 = blockIdx.x * 128, m0 = blockIdx.y * 128;
  if (tid < 32) ws_s[tid] = ws[tid * 32 + blockIdx.x];

  const int wv = tid >> 6, lane = tid & 63;
  const int quad = lane >> 4, l16 = lane & 15;
  const int wm = wv >> 1, wn = wv & 1;

  // staging: xor-swizzle the GLOBAL chunk (LDS side is fixed lane*16)
  const int swc = (tid & 7) ^ ((tid >> 3) & 7);
  const uint8_t* gA = qa + (size_t)(m0 + (tid >> 3)) * H + swc * 16;
  const uint8_t* gB = wt + (size_t)(n0 + (tid >> 3)) * H + swc * 16;
  const uint8_t* gS = (const uint8_t*)sxT + (size_t)m0 * 4 + lane * 16;
  uint8_t* lA = sA + wv * 1024;
  uint8_t* lB = sB + wv * 1024;

  // fragment LDS chunk offsets: global chunk (quad*2+ksp) xor-swizzled by row
  int offp[2];
#pragma unroll
  for (int ksp = 0; ksp < 2; ++ksp)
    offp[ksp] = (((quad * 2 + ksp) ^ (l16 & 7)) << 4);
  const int arow = (wm * 64 + l16) * 128;
  const int brow = (wn * 64 + l16) * 128;
  const int scoff = wm * 64 + quad * 4;

  const v4f zf = {0.f, 0.f, 0.f, 0.f};
  v4f acc[4][4];
#pragma unroll
  for (int i = 0; i < 4; ++i)
#pragma unroll
    for (int j = 0; j < 4; ++j) acc[i][j] = zf;

  for (int kb = 0; kb < 32; ++kb) {
#pragma unroll
    for (int i = 0; i < 4; ++i) {
      gload16(gA + (size_t)i * (32 * H), lA + i * 4096);
      gload16(gB + (size_t)i * (32 * H), lB + i * 4096);
    }
    if (wv == 0 && lane < 32) gload16(gS + (size_t)kb * 16384, (uint8_t*)scb);
    gA += 128;
    gB += 128;
    __syncthreads();

    const float wsk = ws_s[kb];
    v2l bf[4][2];
#pragma unroll
    for (int tc = 0; tc < 4; ++tc)
#pragma unroll
      for (int ksp = 0; ksp < 2; ++ksp)
        bf[tc][ksp] = *(const v2l*)(sB + brow + tc * 2048 + offp[ksp]);

#pragma unroll
    for (int tr = 0; tr < 4; ++tr) {
      const v2l a0 = *(const v2l*)(sA + arow + tr * 2048 + offp[0]);
      const v2l a1 = *(const v2l*)(sA + arow + tr * 2048 + offp[1]);
      const v4f s4 = *(const v4f*)(scb + scoff + tr * 16) * wsk;
#pragma unroll
      for (int tc = 0; tc < 4; ++tc) {
        v4f p = __builtin_amdgcn_mfma_f32_16x16x32_fp8_fp8(a0.x, bf[tc][0].x, zf, 0, 0, 0);
        p = __builtin_amdgcn_mfma_f32_16x16x32_fp8_fp8(a0.y, bf[tc][0].y, p, 0, 0, 0);
        p = __builtin_amdgcn_mfma_f32_16x16x32_fp8_fp8(a1.x, bf[tc][1].x, p, 0, 0, 0);
        p = __builtin_amdgcn_mfma_f32_16x16x32_fp8_fp8(a1.y, bf[tc][1].y, p, 0, 0, 0);
        acc[tr][tc] += p * s4;
      }
    }
    __syncthreads();
  }

  // epilogue: add residual (relu(x) for layer 0)
  const int mB = m0 + wm * 64 + quad * 4;
  const int nB = n0 + wn * 64 + l16;
#pragma unroll
  for (int tr = 0; tr < 4; ++tr) {
#pragma unroll
    for (int r = 0; r < 4; ++r) {
      const size_t rowOff = (size_t)(mB + tr * 16 + r) * H;
#pragma unroll
      for (int tc = 0; tc < 4; ++tc) {
        const size_t idx = rowOff + nB + tc * 16;
        float rv = resid[idx];
        if (relu) rv = fmaxf(rv, 0.f);
        outp[idx] = acc[tr][tc][r] + rv;
      }
    }
  }
}

extern "C" void kernel_launch(void* const* d_in, const int* in_sizes, int n_in,
                              void* d_out, int out_size, void* d_ws, size_t ws_size,
                              hipStream_t stream) {
  const float* x   = (const float*)d_in[0];
  const float* w0  = (const float*)d_in[1];
  const float* ws0 = (const float*)d_in[2];
  const float* w1  = (const float*)d_in[3];
  const float* ws1 = (const float*)d_in[4];
  const float* w2  = (const float*)d_in[5];
  const float* ws2 = (const float*)d_in[6];
  const float* nw0 = (const float*)d_in[7];
  const float* nw1 = (const float*)d_in[8];
  const float* nw2 = (const float*)d_in[9];
  const float* nw3 = (const float*)d_in[10];
  float* R = (float*)d_out;  // residual lives in d_out (in-place)

  uint8_t* base = (uint8_t*)d_ws;
  uint8_t* wq0 = base;
  uint8_t* wq1 = base + ((size_t)16 << 20);
  uint8_t* wq2 = base + ((size_t)32 << 20);
  uint8_t* qa  = base + ((size_t)48 << 20);
  float* sa    = (float*)(base + ((size_t)64 << 20));  // sxT[32][4096]

  conv_w_kernel<<<dim3(64, 64, 3), 256, 0, stream>>>(w0, w1, w2, wq0, wq1, wq2);

  quant_kernel<<<4096, 256, 0, stream>>>(x, nw0, qa, sa, 1);
  gemm_kernel<<<dim3(32, 32), 256, 0, stream>>>(qa, sa, wq0, ws0, x, R, 1);

  quant_kernel<<<4096, 256, 0, stream>>>(R, nw1, qa, sa, 0);
  gemm_kernel<<<dim3(32, 32), 256, 0, stream>>>(qa, sa, wq1, ws1, R, R, 0);

  quant_kernel<<<4096, 256, 0, stream>>>(R, nw2, qa, sa, 0);
  gemm_kernel<<<dim3(32, 32), 256, 0, stream>>>(qa, sa, wq2, ws2, R, R, 0);

  norm_kernel<<<4096, 256, 0, stream>>>(R, nw3);
}